// Round 6
// baseline (252.192 us; speedup 1.0000x reference)
//
#include <hip/hip_runtime.h>
#include <hip/hip_bf16.h>

#define M_DIM 12608   // 64*197
#define K_DIM 768
#define N_DIM 3072
#define M_PAD 12800   // 50*256
#define BM 256
#define BN 128
#define BK 32
#define NT (K_DIM / BK)     // 24 K-tiles
#define MBLK (M_PAD / BM)   // 50
#define NBLK (N_DIM / BN)   // 24
#define NWG (MBLK * NBLK)   // 1200, divisible by 8

typedef __attribute__((ext_vector_type(8))) short bf16x8;
typedef __attribute__((ext_vector_type(16))) float f32x16;

__device__ __forceinline__ void gload_lds16(const void* g, void* l) {
  __builtin_amdgcn_global_load_lds(
      (const __attribute__((address_space(1))) unsigned int*)g,
      (__attribute__((address_space(3))) unsigned int*)l,
      16, 0, 0);
}

// Fused convert: blocks [0, GX) do x fp32->bf16 (+M_PAD zero tail),
// blocks [GX, GX+GW) do 2:4 mask + w fp32->bf16.
#define GX 4800   // M_PAD*K/8/256
#define GW 2304   // N*(K/4)/256
__global__ void cvt_fused(const float* __restrict__ x, const float* __restrict__ w,
                          __hip_bfloat16* __restrict__ xb, __hip_bfloat16* __restrict__ wb) {
  if (blockIdx.x < GX) {
    size_t i = ((size_t)blockIdx.x * 256 + threadIdx.x) * 8;
    union { __hip_bfloat16 h[8]; uint4 u; } o;
    if (i < (size_t)M_DIM * K_DIM) {
      float4 a = *(const float4*)(x + i);
      float4 b = *(const float4*)(x + i + 4);
      o.h[0] = __float2bfloat16(a.x); o.h[1] = __float2bfloat16(a.y);
      o.h[2] = __float2bfloat16(a.z); o.h[3] = __float2bfloat16(a.w);
      o.h[4] = __float2bfloat16(b.x); o.h[5] = __float2bfloat16(b.y);
      o.h[6] = __float2bfloat16(b.z); o.h[7] = __float2bfloat16(b.w);
    } else {
      o.u = make_uint4(0, 0, 0, 0);
    }
    *(uint4*)(xb + i) = o.u;
  } else {
    size_t g = ((size_t)(blockIdx.x - GX) * 256 + threadIdx.x);
    float4 v = *(const float4*)(w + g * 4);
    float val[4] = {v.x, v.y, v.z, v.w};
    float a[4] = {fabsf(v.x), fabsf(v.y), fabsf(v.z), fabsf(v.w)};
    union { __hip_bfloat16 h[4]; uint2 u; } o;
#pragma unroll
    for (int i = 0; i < 4; ++i) {
      int rank = 0;
#pragma unroll
      for (int j = 0; j < 4; ++j)
        rank += (a[j] > a[i]) || (a[j] == a[i] && j > i);
      o.h[i] = __float2bfloat16(rank < 2 ? val[i] : 0.0f);
    }
    *(uint2*)(wb + g * 4) = o.u;
  }
}

// 256x128 tile, BK=32, 8 waves (4M x 2N), per-wave 64x64 via 2x2 frags of
// v_mfma_f32_32x32x16_bf16 (2.4x fewer MFMA instrs + 33% fewer ds_reads than
// the 16x16x32 equivalent; highest measured ceiling 2382 TF).
// 3-deep LDS pipeline (3 x 24KB = 72KB -> 2 blocks/CU = 4 waves/SIMD),
// counted vmcnt(3) + one raw s_barrier per K-tile, setprio on MFMA cluster,
// direct-store epilogue writing full 128B lines per instruction.
//
// LDS buffer q at q*24576: A 256x32 bf16 (16KB) @ +0, B 128x32 (8KB) @ +16384.
// Swizzle: element (row, kg) at byte row*64 + (kg ^ ((row>>1)&3))*16.
// b128-read conflict floor check: 64 lanes -> 8 x 16B slots mod 128, exactly
// 8 lanes/slot uniform = the 1024B/128B minimum bank-cycles (0 extra; same
// family measured 0 conflicts in rounds 3/5).
// gload_lds writes linearly; swizzle applied by pre-swizzling the per-lane
// GLOBAL source k-group (both-sides rule #21).
//
// 32x32x16 fragment use: A lane&31 = row, lane>>5 selects the 8-elem k-half;
// B symmetric. Any within-group k-permutation cancels between A and B (both
// supply the same k-group), so only row/col<->lane mapping matters.
// C/D layout (HW-verified m74/m101): col=lane&31, row=(reg&3)+8*(reg>>2)+4*(lane>>5).
__global__ __launch_bounds__(512, 4) void gemm_bt(
    const __hip_bfloat16* __restrict__ A,   // [M_PAD][K]
    const __hip_bfloat16* __restrict__ B,   // [N][K]
    const float* __restrict__ bias,         // [N]
    float* __restrict__ C)                  // [M][N]
{
  extern __shared__ char smem[];   // 73728

  const int tid  = threadIdx.x;
  const int lane = tid & 63;
  const int wave = tid >> 6;   // 0..7
  const int wm   = wave >> 1;  // 0..3 (64-row band)
  const int wn   = wave & 1;   // 0..1 (64-col band)

  // bijective XCD swizzle: 1200 = 8*150; consecutive swz iterate N fastest
  // (A band 384KB L2-resident per XCD; B walks 24 tiles -> lowest FETCH, r1).
  const int wg  = blockIdx.x;
  const int swz = (wg & 7) * (NWG / 8) + (wg >> 3);
  const int tile_m = (swz / NBLK) * BM;
  const int tile_n = (swz % NBLK) * BN;

  // ---- staging geometry: one gload call = 8 waves x 16 rows x 64B (128 rows).
  // lane l -> row offset l>>2, slot p = l&3; global k-group = p ^ f(row),
  // f(row) = (row>>1)&3 = ((l>>2)>>1)&3 = (l>>3)&3 (row bases multiple of 16).
  const int l4 = lane >> 2;
  const int gk = ((lane & 3) ^ ((lane >> 3) & 3)) * 8;
  const __hip_bfloat16* ag = A + (size_t)(tile_m + wave * 16 + l4) * K_DIM + gk;
  const __hip_bfloat16* bg = B + (size_t)(tile_n + wave * 16 + l4) * K_DIM + gk;

  // ---- fragment read geometry
  const int half = lane >> 5;       // k-half (8 elems)
  const int lrow = lane & 31;
  const int arow0 = wm * 64 + lrow;           // + mi*32 (f unchanged: 32%4==0 after >>1)
  const int brow0 = wn * 64 + lrow;           // + ni*32
  const int af_ = (arow0 >> 1) & 3;
  const int bf_ = (brow0 >> 1) & 3;
  // slot for (j, half): (j*2 + half) ^ f
  int aoff[2][2], boff[2][2];   // [j][mi/ni]
#pragma unroll
  for (int j = 0; j < 2; ++j)
#pragma unroll
    for (int s = 0; s < 2; ++s) {
      aoff[j][s] = (arow0 + s * 32) * 64 + (((j * 2 + half) ^ af_) << 4);
      boff[j][s] = 16384 + (brow0 + s * 32) * 64 + (((j * 2 + half) ^ bf_) << 4);
    }

  f32x16 acc[2][2] = {};

  // ---- prologue: stage tiles 0 and 1 into buffers 0 and 1 (3 loads each)
  {
    char* b0 = smem;
    gload_lds16(ag, b0 + wave * 1024);
    gload_lds16(ag + (size_t)128 * K_DIM, b0 + 8192 + wave * 1024);
    gload_lds16(bg, b0 + 16384 + wave * 1024);
    char* b1 = smem + 24576;
    gload_lds16(ag + BK, b1 + wave * 1024);
    gload_lds16(ag + (size_t)128 * K_DIM + BK, b1 + 8192 + wave * 1024);
    gload_lds16(bg + BK, b1 + 16384 + wave * 1024);
  }

  // ---- main loop: tile t in buf (t%3); stage t+2 into buf ((t+2)%3).
  // Head wait: outstanding = stage(t) [if t<2: not yet retired] .. in steady
  // state = {stage(t),stage(t+1)} = 6 -> VM(3) retires stage(t) (per-wave
  // FIFO). Barrier then (a) makes all waves' tile-t LDS writes visible,
  // (b) proves all waves' tile t-1 ds_reads retired (lgkm before their t-1
  // MFMAs, which precede this barrier) -> overwriting buf((t+2)%3) ==
  // buf((t-1)%3) after the barrier is safe.
#pragma unroll 3
  for (int t = 0; t < NT; ++t) {
    if (t < NT - 1) { asm volatile("s_waitcnt vmcnt(3)" ::: "memory"); }
    else            { asm volatile("s_waitcnt vmcnt(0)" ::: "memory"); }
    __builtin_amdgcn_s_barrier();

    if (t + 2 < NT) {
      char* nb = smem + ((t + 2) % 3) * 24576;
      const size_t off = (size_t)(t + 2) * BK;
      gload_lds16(ag + off, nb + wave * 1024);
      gload_lds16(ag + (size_t)128 * K_DIM + off, nb + 8192 + wave * 1024);
      gload_lds16(bg + off, nb + 16384 + wave * 1024);
    }

    const char* bq = smem + (t % 3) * 24576;
    bf16x8 afr[2][2], bfr[2][2];   // [j][mi/ni]
#pragma unroll
    for (int j = 0; j < 2; ++j)
#pragma unroll
      for (int s = 0; s < 2; ++s) {
        afr[j][s] = *(const bf16x8*)(bq + aoff[j][s]);
        bfr[j][s] = *(const bf16x8*)(bq + boff[j][s]);
      }
    __builtin_amdgcn_s_setprio(1);
#pragma unroll
    for (int mi = 0; mi < 2; ++mi)
#pragma unroll
      for (int ni = 0; ni < 2; ++ni) {
        acc[mi][ni] = __builtin_amdgcn_mfma_f32_32x32x16_bf16(afr[0][mi], bfr[0][ni], acc[mi][ni], 0, 0, 0);
        acc[mi][ni] = __builtin_amdgcn_mfma_f32_32x32x16_bf16(afr[1][mi], bfr[1][ni], acc[mi][ni], 0, 0, 0);
      }
    __builtin_amdgcn_s_setprio(0);
  }

  // ---- epilogue: direct stores. C/D: col=lane&31, row=(reg&3)+8*(reg>>2)+4*half.
  // One store inst (fixed reg) = 2 rows x 32 consecutive floats = 2 full 128B lines.
  const int ccol = lane & 31;
  float bv[2];
#pragma unroll
  for (int ni = 0; ni < 2; ++ni)
    bv[ni] = bias[tile_n + wn * 64 + ni * 32 + ccol];

#pragma unroll
  for (int mi = 0; mi < 2; ++mi) {
    const int rb = tile_m + wm * 64 + mi * 32 + half * 4;
#pragma unroll
    for (int ni = 0; ni < 2; ++ni) {
      float* cp = C + (size_t)0 * N_DIM + tile_n + wn * 64 + ni * 32 + ccol;
#pragma unroll
      for (int reg = 0; reg < 16; ++reg) {
        const int grow = rb + (reg & 3) + 8 * (reg >> 2);
        if (grow < M_DIM)
          cp[(size_t)grow * N_DIM] = acc[mi][ni][reg] + bv[ni];
      }
    }
  }
}

extern "C" void kernel_launch(void* const* d_in, const int* in_sizes, int n_in,
                              void* d_out, int out_size, void* d_ws, size_t ws_size,
                              hipStream_t stream) {
  const float* x    = (const float*)d_in[0];
  const float* w    = (const float*)d_in[1];
  const float* bias = (const float*)d_in[2];
  float* out = (float*)d_out;

  __hip_bfloat16* xb = (__hip_bfloat16*)d_ws;                  // [M_PAD][K]
  __hip_bfloat16* wb = xb + (size_t)M_PAD * K_DIM;             // [N][K]

  static bool attr_set = false;
  if (!attr_set) {
    hipFuncSetAttribute(reinterpret_cast<const void*>(gemm_bt),
                        hipFuncAttributeMaxDynamicSharedMemorySize, 73728);
    attr_set = true;
  }

  cvt_fused<<<GX + GW, 256, 0, stream>>>(x, w, xb, wb);
  gemm_bt<<<NWG, 512, 73728, stream>>>(xb, wb, bias, out);
}